// Round 8
// baseline (294.296 us; speedup 1.0000x reference)
//
#include <hip/hip_runtime.h>

#define HID    192
#define HID2   384
#define NEDGES 262144
#define NSEG   16384
#define MB     64
#define NBLK   (NEDGES / MB)   // 4096

#define ALD   200              // embed-tile LDS row stride (bf16 elems)
#define H1LD  408              // H1 LDS row stride
#define MH2   26112            // mean-H2 region start; 4 rows x 192
#define SMEM2 26880            // 53760 B -> 3 blocks/CU at 256 thr

typedef __bf16 bf16;
typedef __bf16 bv8 __attribute__((ext_vector_type(8)));
typedef __bf16 bv4 __attribute__((ext_vector_type(4)));
typedef float f32x4 __attribute__((ext_vector_type(4)));

__device__ __forceinline__ float gelu_fast(float x) {
    float x2 = x * x;
    float u2 = 1.5957691216057308f * x * __builtin_fmaf(0.044715f, x2, 1.0f);
    float e  = __expf(u2);
    float inv = __builtin_amdgcn_rcpf(e + 1.0f);
    return __builtin_fmaf(-x, inv, x);
}

// paired sincos embed: angles a0..a0+7 (a0 % 8 == 0, flattened angle space 0..95,
// dim = a0>>5, f = a0&31). Writes sin8 at col dim*64+f, cos8 at col dim*64+32+f.
__device__ __forceinline__ void embed_pair(bf16* row, float p0, float p1, float p2, int a0) {
    const int dim = a0 >> 5;
    const int f0  = a0 & 31;
    const float pv = (dim == 0) ? p0 : ((dim == 1) ? p1 : p2);
    float om = exp2f(-0.4152410118609203f * (float)f0);   // 10000^(-f0/32)
    bv8 sv, cv;
    #pragma unroll
    for (int j = 0; j < 8; ++j) {
        const float x = pv * om;
        sv[j] = (bf16)__sinf(x);
        cv[j] = (bf16)__cosf(x);
        om *= 0.74989420933245582f;                       // 10000^(-1/32)
    }
    *reinterpret_cast<bv8*>(row + dim * 64 + f0)      = sv;
    *reinterpret_cast<bv8*>(row + dim * 64 + 32 + f0) = cv;
}

// ---- K0 prep: blocks 0-251 = tiled W transpose+cast; blocks 252-1275 = dstC ----
__global__ __launch_bounds__(256)
void prep_kernel(const float* __restrict__ W1, const float* __restrict__ W2,
                 const float* __restrict__ W3,
                 const float* __restrict__ pos, const int* __restrict__ edges,
                 bf16* __restrict__ W1T, bf16* __restrict__ W2T, bf16* __restrict__ W3T,
                 bf16* __restrict__ dstC) {
    if (blockIdx.x < 252) {
        __shared__ float t[32][33];
        int b = blockIdx.x;
        const float* S; bf16* D; int K, N, tk, tn;
        if (b < 144)      { S = W1; D = W1T; K = 384; N = 384; tk = (b / 12) * 32; tn = (b % 12) * 32; }
        else if (b < 216) { b -= 144; S = W2; D = W2T; K = 384; N = 192; tk = (b / 6) * 32; tn = (b % 6) * 32; }
        else              { b -= 216; S = W3; D = W3T; K = 192; N = 192; tk = (b / 6) * 32; tn = (b % 6) * 32; }
        const int c = threadIdx.x & 31, r0 = threadIdx.x >> 5;
        #pragma unroll
        for (int i = 0; i < 4; ++i)
            t[r0 + i * 8][c] = S[(size_t)(tk + r0 + i * 8) * N + tn + c];
        __syncthreads();
        #pragma unroll
        for (int i = 0; i < 4; ++i)
            D[(size_t)(tn + r0 + i * 8) * K + tk + c] = (bf16)t[c][r0 + i * 8];
        return;
    }
    // ---- dstC[seg][0:384] = embed(dst_node(seg)) @ W1[192:384,:], 16 segs/block ----
    __shared__ __align__(16) bf16 smem[16 * ALD];
    const int tid = threadIdx.x, w = tid >> 6, lane = tid & 63;
    const int quad = lane >> 4, l15 = lane & 15;
    const int s0 = (blockIdx.x - 252) * 16;
    if (tid < 64) {                                    // 16 rows x 4 parts x 24 angles
        const int r = tid >> 2, p = tid & 3;
        const int node = edges[2 * ((s0 + r) * 16)];   // dst node of segment s0+r
        const float p0 = pos[node * 3 + 0], p1 = pos[node * 3 + 1], p2 = pos[node * 3 + 2];
        bf16* row = smem + r * ALD;
        #pragma unroll
        for (int g = 0; g < 3; ++g)
            embed_pair(row, p0, p1, p2, p * 24 + g * 8);
    }
    __syncthreads();
    const f32x4 fz = {0.f, 0.f, 0.f, 0.f};
    f32x4 acc[6];
    #pragma unroll
    for (int mc = 0; mc < 6; ++mc) acc[mc] = fz;
    const bf16* xb = smem + l15 * ALD + quad * 8;
    for (int kt = 0; kt < 6; ++kt) {
        bv8 x = *reinterpret_cast<const bv8*>(xb + kt * 32);
        #pragma unroll
        for (int mc = 0; mc < 6; ++mc) {
            bv8 a;                                     // A-frag = W1 col slice (coalesced per j)
            const int col = w * 96 + mc * 16 + l15;
            #pragma unroll
            for (int j = 0; j < 8; ++j)
                a[j] = (bf16)W1[(size_t)(192 + kt * 32 + quad * 8 + j) * HID2 + col];
            acc[mc] = __builtin_amdgcn_mfma_f32_16x16x32_bf16(a, x, acc[mc], 0, 0, 0);
        }
    }
    #pragma unroll
    for (int mc = 0; mc < 6; ++mc) {
        bv4 pk;
        #pragma unroll
        for (int r = 0; r < 4; ++r) pk[r] = (bf16)acc[mc][r];
        *reinterpret_cast<bv4*>(dstC + (size_t)(s0 + l15) * HID2
                                + w * 96 + mc * 16 + quad * 4) = pk;
    }
}

// ---- K1: fused embed -> GEMM1(sw) -> +dstC+gelu -> GEMM2 -> gelu+mean -> GEMM3 -> out ----
__global__ __launch_bounds__(256, 3)
void fused_mlp_kernel(const float* __restrict__ pos, const int* __restrict__ edges,
                      const bf16* __restrict__ W1T, const float* __restrict__ b1,
                      const bf16* __restrict__ W2T, const float* __restrict__ b2,
                      const bf16* __restrict__ W3T, const float* __restrict__ b3,
                      const bf16* __restrict__ dstC, float* __restrict__ out) {
    __shared__ __align__(16) bf16 smem[SMEM2];
    const int tid = threadIdx.x, w = tid >> 6, lane = tid & 63;
    const int quad = lane >> 4, l15 = lane & 15, blk = blockIdx.x;

    // P1: A = embed(src) 64x192, 4 thr/row, paired sin/cos (24 angles -> 48 cols each)
    {
        const int r = tid >> 2, p = tid & 3;
        const int node = edges[2 * (blk * MB + r) + 1];
        const float p0 = pos[node * 3 + 0], p1 = pos[node * 3 + 1], p2 = pos[node * 3 + 2];
        bf16* row = smem + r * ALD;
        #pragma unroll
        for (int g = 0; g < 3; ++g)
            embed_pair(row, p0, p1, p2, p * 24 + g * 8);
    }
    __syncthreads();   // b1

    const f32x4 fz = {0.f, 0.f, 0.f, 0.f};

    // P2: GEMM1 swapped (A=W1T rows = outcols w*96..+95), all 64 edges, K=192
    f32x4 acc1[6][4];
    #pragma unroll
    for (int mc = 0; mc < 6; ++mc)
        #pragma unroll
        for (int ne = 0; ne < 4; ++ne) acc1[mc][ne] = fz;
    {
        const bf16* wb = W1T + (size_t)(w * 96 + l15) * HID2 + quad * 8;
        const bf16* xb = smem + l15 * ALD + quad * 8;
        for (int kt = 0; kt < 6; ++kt) {
            bv8 x[4];
            #pragma unroll
            for (int ne = 0; ne < 4; ++ne)
                x[ne] = *reinterpret_cast<const bv8*>(xb + ne * 16 * ALD + kt * 32);
            #pragma unroll
            for (int mc = 0; mc < 6; ++mc) {
                bv8 a = *reinterpret_cast<const bv8*>(wb + mc * 16 * HID2 + kt * 32);
                #pragma unroll
                for (int ne = 0; ne < 4; ++ne)
                    acc1[mc][ne] = __builtin_amdgcn_mfma_f32_16x16x32_bf16(a, x[ne], acc1[mc][ne], 0, 0, 0);
            }
        }
    }

    // Hoist dstC + b1 loads (global, independent of barrier) to overlap b2 wait
    bv4  dcH[6][4];
    f32x4 b1H[6];
    #pragma unroll
    for (int mc = 0; mc < 6; ++mc) {
        const int cb = w * 96 + mc * 16 + quad * 4;
        b1H[mc] = *reinterpret_cast<const f32x4*>(b1 + cb);
        #pragma unroll
        for (int ne = 0; ne < 4; ++ne)
            dcH[mc][ne] = *reinterpret_cast<const bv4*>(dstC + (size_t)(blk * 4 + ne) * HID2 + cb);
    }
    __syncthreads();   // b2: A dead (H1 overlays it)

    // P3: H1[edge][outcol] = gelu(acc1 + dstC[seg] + b1), b64 LDS stores
    #pragma unroll
    for (int mc = 0; mc < 6; ++mc) {
        const int cb = w * 96 + mc * 16 + quad * 4;
        #pragma unroll
        for (int ne = 0; ne < 4; ++ne) {   // seg = ne
            bv4 o;
            #pragma unroll
            for (int r = 0; r < 4; ++r)
                o[r] = (bf16)gelu_fast(acc1[mc][ne][r] + (float)dcH[mc][ne][r] + b1H[mc][r]);
            *reinterpret_cast<bv4*>(smem + (ne * 16 + l15) * H1LD + cb) = o;
        }
    }

    // Hoist b2 bias before b3
    float b2H[3];
    #pragma unroll
    for (int nc = 0; nc < 3; ++nc) b2H[nc] = b2[w * 48 + nc * 16 + l15];
    __syncthreads();   // b3: H1 complete

    // P4: GEMM2 normal (A=H1 rows, B=W2T), K=384, wave covers 48 N-cols
    f32x4 acc2[4][3];
    #pragma unroll
    for (int m = 0; m < 4; ++m)
        #pragma unroll
        for (int nc = 0; nc < 3; ++nc) acc2[m][nc] = fz;
    {
        const bf16* hb = smem + l15 * H1LD + quad * 8;
        const bf16* wb = W2T + (size_t)(w * 48 + l15) * HID2 + quad * 8;
        for (int kt = 0; kt < 12; ++kt) {
            bv8 h[4];
            #pragma unroll
            for (int m = 0; m < 4; ++m)
                h[m] = *reinterpret_cast<const bv8*>(hb + m * 16 * H1LD + kt * 32);
            #pragma unroll
            for (int nc = 0; nc < 3; ++nc) {
                bv8 b = *reinterpret_cast<const bv8*>(wb + nc * 16 * HID2 + kt * 32);
                #pragma unroll
                for (int m = 0; m < 4; ++m)
                    acc2[m][nc] = __builtin_amdgcn_mfma_f32_16x16x32_bf16(h[m], b, acc2[m][nc], 0, 0, 0);
            }
        }
    }

    // P5: gelu2 + segment mean (m-tile == segment) -> mh2 in LDS
    #pragma unroll
    for (int nc = 0; nc < 3; ++nc) {
        const int colv = w * 48 + nc * 16 + l15;
        #pragma unroll
        for (int m = 0; m < 4; ++m) {
            float s = gelu_fast(acc2[m][nc][0] + b2H[nc]) + gelu_fast(acc2[m][nc][1] + b2H[nc])
                    + gelu_fast(acc2[m][nc][2] + b2H[nc]) + gelu_fast(acc2[m][nc][3] + b2H[nc]);
            s += __shfl_xor(s, 16);
            s += __shfl_xor(s, 32);
            if (quad == 0)
                smem[MH2 + m * HID + colv] = (bf16)(s * 0.0625f);
        }
    }

    // Hoist W3 fragments + b3 bias (global, no LDS dependency) to overlap b4 wait
    bv8 w3H[3][6];
    {
        const bf16* wb = W3T + (size_t)(w * 48 + l15) * HID + quad * 8;
        #pragma unroll
        for (int nc = 0; nc < 3; ++nc)
            #pragma unroll
            for (int kt = 0; kt < 6; ++kt)
                w3H[nc][kt] = *reinterpret_cast<const bv8*>(wb + nc * 16 * HID + kt * 32);
    }
    float b3H[3];
    #pragma unroll
    for (int nc = 0; nc < 3; ++nc) b3H[nc] = b3[w * 48 + nc * 16 + l15];
    __syncthreads();   // b4: mh2 complete

    // P6: GEMM3 on means (A rows = mh2[l15&3], B = W3 frags in regs), + b3 -> out
    {
        f32x4 acc3[3];
        #pragma unroll
        for (int nc = 0; nc < 3; ++nc) acc3[nc] = fz;
        const bf16* ab = smem + MH2 + (l15 & 3) * HID + quad * 8;
        for (int kt = 0; kt < 6; ++kt) {
            bv8 a = *reinterpret_cast<const bv8*>(ab + kt * 32);
            #pragma unroll
            for (int nc = 0; nc < 3; ++nc)
                acc3[nc] = __builtin_amdgcn_mfma_f32_16x16x32_bf16(a, w3H[nc][kt], acc3[nc], 0, 0, 0);
        }
        if (quad == 0) {
            #pragma unroll
            for (int nc = 0; nc < 3; ++nc) {
                const int col = w * 48 + nc * 16 + l15;
                #pragma unroll
                for (int r = 0; r < 4; ++r)   // C row r (quad 0) == segment r
                    out[(size_t)(blk * 4 + r) * HID + col] = acc3[nc][r] + b3H[nc];
            }
        }
    }
}

extern "C" void kernel_launch(void* const* d_in, const int* in_sizes, int n_in,
                              void* d_out, int out_size, void* d_ws, size_t ws_size,
                              hipStream_t stream) {
    const float* mesh_pos = (const float*)d_in[0];
    const int*   edges    = (const int*)  d_in[1];
    // d_in[2] = batch_idx (unused)
    const float* W1 = (const float*)d_in[3];
    const float* b1 = (const float*)d_in[4];
    const float* W2 = (const float*)d_in[5];
    const float* b2 = (const float*)d_in[6];
    const float* W3 = (const float*)d_in[7];
    const float* b3 = (const float*)d_in[8];
    float* out = (float*)d_out;

    // ws layout (bf16): W1T 147456 | W2T 73728 | W3T 36864 | dstC 16384*384  (~13.1 MB)
    bf16* W1T  = (bf16*)d_ws;
    bf16* W2T  = W1T + 147456;
    bf16* W3T  = W2T + 73728;
    bf16* dstC = W3T + 36864;

    prep_kernel<<<252 + NSEG / 16, 256, 0, stream>>>(W1, W2, W3, mesh_pos, edges,
                                                     W1T, W2T, W3T, dstC);
    fused_mlp_kernel<<<NBLK, 256, 0, stream>>>(mesh_pos, edges, W1T, b1, W2T, b2, W3T, b3,
                                               dstC, out);
}